// Round 10
// baseline (802.521 us; speedup 1.0000x reference)
//
#include <hip/hip_runtime.h>
#include <cstdint>

#define HID 128
#define HC  130
#define NIO 128
#define DENSW 64     // dense ELL width (max in-degree ~45 for Poisson(16))
#define SUBB 8       // sub-cursors per (xcd,bucket): kills same-address atomic serialization
#define BCAP_S 128   // per-(xcd,sub,bucket) capacity; mean ~32 (+17 sigma), 25.6MB total

typedef _Float16 f16;
typedef _Float16 f16x2 __attribute__((ext_vector_type(2)));
typedef _Float16 f16x4 __attribute__((ext_vector_type(4)));
typedef _Float16 f16x8 __attribute__((ext_vector_type(8)));
typedef float    f32x4 __attribute__((ext_vector_type(4)));

__device__ __forceinline__ float sigm(float z) {
  return 1.0f / (1.0f + __expf(-z));
}

__device__ __forceinline__ int xcc_id() {
  int x;
  asm volatile("s_getreg_b32 %0, hwreg(HW_REG_XCC_ID)" : "=s"(x));
  return x & 7;
}

// Packed f16 max: v_pk_max_f16 does 2 elements/op (ternary lowers to
// v_cmp+v_cndmask = 4x the VALU). Inputs finite (sigmoid/LN outputs).
__device__ __forceinline__ f16x8 max8(f16x8 a, f16x8 b) {
  union P { f16x8 h; f16x2 p[4]; } A, B, O;
  A.h = a; B.h = b;
  #pragma unroll
  for (int i = 0; i < 4; ++i)
    asm("v_pk_max_f16 %0, %1, %2" : "=v"(O.p[i]) : "v"(A.p[i]), "v"(B.p[i]));
  return O.h;
}

// ---------------- prep mega-kernel ----------------
struct WDesc { const float* src; f16* dst; int K, NC, Kpad, NCpad; };
struct WAll { WDesc m[9]; };

__global__ __launch_bounds__(256) void prep_kernel(
    const float* __restrict__ x, f16* __restrict__ x16, f16* __restrict__ xg,
    int n, WAll wa, int* __restrict__ bcnt, int nzero, int gX) {
  const int bb = blockIdx.x;
  const int t = threadIdx.x;
  if (bb < gX) {
    int idx = bb * 256 + t;
    if (idx >= n * 20) return;
    int r = idx / 20, g = idx - r * 20;
    int c0 = g * 8;
    f16x8 o;
    #pragma unroll
    for (int j = 0; j < 8; ++j) {
      int c = c0 + j;
      o[j] = (f16)((c < HC) ? x[(size_t)r * HC + c] : 0.0f);
    }
    *(f16x8*)&x16[(size_t)r * 160 + c0] = o;
    if (c0 >= 136) {
      f16x8 z = (f16x8){0,0,0,0,0,0,0,0};
      *(f16x8*)&xg[(size_t)r * 160 + c0] = z;
    } else if (c0 == 128) {
      #pragma unroll
      for (int c = 130; c < 136; ++c) xg[(size_t)r * 160 + c] = (f16)0.0f;
    }
  } else if (bb < gX + 90) {
    const int wb = bb - gX;
    const WDesc d = wa.m[wb / 10];
    const int KST = d.Kpad >> 5;
    const int total = (d.NCpad >> 4) * KST * 64;
    int idx = (wb % 10) * 256 + t;
    if (idx >= total) return;
    int nt  = idx / (KST * 64);
    int rem = idx - nt * (KST * 64);
    int ks  = rem >> 6;
    int l   = rem & 63;
    int nn  = nt * 16 + (l & 15);
    int k0  = ks * 32 + (l >> 4) * 8;
    f16x8 o;
    #pragma unroll
    for (int j = 0; j < 8; ++j) {
      int k = k0 + j;
      float v = (k < d.K && nn < d.NC) ? d.src[(size_t)k * d.NC + nn] : 0.0f;
      o[j] = (f16)v;
    }
    *((f16x8*)d.dst + idx) = o;
  } else {
    int i = (bb - gX - 90) * 256 + t;
    if (i < nzero) bcnt[i] = 0;
  }
}

// ---------------- graph build: two-level binning ----------------
__global__ void binscatter_kernel(const int* __restrict__ row, const int* __restrict__ col,
    int* __restrict__ bcnt, unsigned* __restrict__ bucket, int e, int nb) {
  const int g0 = xcc_id() * SUBB + ((blockIdx.x >> 3) & (SUBB - 1));
  int i = blockIdx.x * blockDim.x + threadIdx.x;
  if (i >= e) return;
  int c = col[i], r = row[i];
  int b = c >> 7;
  int cur = atomicAdd(&bcnt[g0 * nb + b], 1);
  if (cur < BCAP_S)
    bucket[((size_t)g0 * nb + b) * BCAP_S + cur] = ((unsigned)r << 7) | (unsigned)(c & 127);
}

__global__ __launch_bounds__(256) void build_kernel(const int* __restrict__ bcnt,
    const unsigned* __restrict__ bucket, int* __restrict__ ncnt,
    int* __restrict__ dense, float* __restrict__ dinv, int n, int nb) {
  __shared__ int lcnt[128];
  const int b = blockIdx.x;
  const int t = threadIdx.x;
  if (t < 128) lcnt[t] = 0;
  __syncthreads();
  const int wv = t >> 6, ln = t & 63;
  #pragma unroll 1
  for (int g = wv * 16; g < wv * 16 + 16; ++g) {
    const int cntg = min(bcnt[g * nb + b], BCAP_S);
    const unsigned* __restrict__ src = bucket + ((size_t)g * nb + b) * BCAP_S;
    for (int idx = ln; idx < cntg; idx += 64) {
      unsigned ev = src[idx];
      int cl = (int)(ev & 127u);
      int r  = (int)(ev >> 7);
      int s = atomicAdd(&lcnt[cl], 1);
      if (s < DENSW) dense[(size_t)((b << 7) + cl) * DENSW + s] = r;
    }
  }
  __syncthreads();
  if (t < 128) {
    int c = (b << 7) + t;
    if (c < n) {
      int cc = min(lcnt[t], DENSW);
      ncnt[c] = cc;
      dinv[c] = rsqrtf((float)(cc + 1));  // +1 self-loop
    }
  }
}

// ---------------- MFMA matmul (standalone; used for gcn1 only) ----------------
template<int KPAD, int RS, int NCPAD, int NC, int MODE, int MROWS>
__global__ __launch_bounds__(256, 4) void mm_mfma(
    const f16* __restrict__ X, const f16* __restrict__ Wt,
    const float* __restrict__ bias, f16* __restrict__ Y,
    const float* __restrict__ dinv, const f16* __restrict__ xor16,
    const float* __restrict__ initial, int n, int ngrid)
{
  static_assert(MODE != 1 || MROWS == 128, "MODE1 only at 128 rows");
  constexpr int KST = KPAD / 32;
  constexpr int NT  = NCPAD / 16;
  constexpr int MT  = MROWS / 64;
  constexpr int RPW = MROWS / 4;
  constexpr int YRS = (MODE == 1) ? 160 : 128;
  constexpr int PSTR = (NCPAD == 128) ? 132 : 148;
  constexpr int LDSH = (NCPAD * KPAD > MROWS * PSTR) ? NCPAD * KPAD : MROWS * PSTR;
  __shared__ __align__(16) f16 Bs[LDSH];

  const int t = threadIdx.x;
  const int wid  = t >> 6;
  const int l    = t & 63;
  const int m15  = l & 15;
  const int quad = l >> 4;
  const int rw   = blockIdx.x * MROWS + wid * RPW;

  constexpr int BSW = NCPAD * KPAD / 8;
  #pragma unroll
  for (int i = 0; i < (BSW + 255) / 256; ++i) {
    int idx = t + i * 256;
    if (BSW % 256 == 0 || idx < BSW)
      ((f16x8*)Bs)[idx] = ((const f16x8*)Wt)[idx];
  }

  const f16* Xr0 = X + (size_t)(rw + m15) * RS;
  const f16* Xr1 = X + (size_t)(rw + 16 + m15) * RS;
  f16x8 a0r[KST], a1r[KST];
  #pragma unroll
  for (int ks = 0; ks < KST; ++ks) {
    const int off = ks * 32 + quad * 8;
    a0r[ks] = *(const f16x8*)(Xr0 + off);
    if constexpr (MT == 2) a1r[ks] = *(const f16x8*)(Xr1 + off);
  }

  constexpr int TPR = 256 / MROWS;
  constexpr int CSP = 128 / TPR;
  const int r  = t / TPR;
  const int cp = t % TPR;
  const int gr = blockIdx.x * MROWS + r;
  float dv = 0.0f;
  if constexpr (MODE == 2) dv = (gr < n) ? dinv[gr] : 0.0f;

  __syncthreads();

  f32x4 acc[MT][NT];
  #pragma unroll
  for (int mt = 0; mt < MT; ++mt)
    #pragma unroll
    for (int nt = 0; nt < NT; ++nt)
      acc[mt][nt] = (f32x4){0.f, 0.f, 0.f, 0.f};

  #pragma unroll
  for (int ks = 0; ks < KST; ++ks) {
    #pragma unroll
    for (int nt = 0; nt < NT; ++nt) {
      f16x8 b = *((const f16x8*)Bs + (nt * KST + ks) * 64 + l);
      acc[0][nt] = __builtin_amdgcn_mfma_f32_16x16x32_f16(a0r[ks], b, acc[0][nt], 0, 0, 0);
      if constexpr (MT == 2)
        acc[1][nt] = __builtin_amdgcn_mfma_f32_16x16x32_f16(a1r[ks], b, acc[1][nt], 0, 0, 0);
    }
  }

  __syncthreads();

  #pragma unroll
  for (int mt = 0; mt < MT; ++mt) {
    #pragma unroll
    for (int reg = 0; reg < 4; ++reg) {
      const int rl = wid * RPW + mt * 16 + quad * 4 + reg;
      #pragma unroll
      for (int nt = 0; nt < NT; ++nt)
        Bs[rl * PSTR + nt * 16 + m15] = (f16)acc[mt][nt][reg];
    }
  }
  __syncthreads();

  if (gr < n) {
    #pragma unroll
    for (int c8 = 0; c8 < CSP / 8; ++c8) {
      const int c0 = cp * CSP + c8 * 8;
      f16x8 v = *(const f16x8*)&Bs[r * PSTR + c0];
      f16x8 o;
      #pragma unroll
      for (int j = 0; j < 8; ++j) {
        float a = (float)v[j];
        if constexpr (MODE == 0) o[j] = (f16)sigm(a + bias[c0 + j]);
        else                     o[j] = (f16)(a * dv);
      }
      *(f16x8*)&Y[(size_t)gr * YRS + c0] = o;
    }
  }
}

// ---------------- fused two-layer MLP ----------------
template<int K1PAD, int RS1, int NC2PAD, int NC2, int MODE2>
__global__ __launch_bounds__(256, 2) void mm_fused(
    const f16* __restrict__ X, const f16* __restrict__ W1t, const f16* __restrict__ W2t,
    const float* __restrict__ b1, const float* __restrict__ b2, f16* __restrict__ Y,
    const f16* __restrict__ xor16, const float* __restrict__ initial, int n, int ngrid)
{
  constexpr int KST1 = K1PAD / 32;
  constexpr int NT1  = 8;
  constexpr int KST2 = 4;
  constexpr int NT2  = NC2PAD / 16;
  constexpr int PSTR1 = 132;
  constexpr int PSTR2 = (NC2PAD == 128) ? 132 : 148;
  constexpr int YRS  = (MODE2 == 1) ? 160 : 128;
  constexpr int W2U  = NC2PAD * 128;
  constexpr int SC_A = K1PAD * 128;
  constexpr int SC_B = 128 * PSTR2;
  constexpr int SCU  = (SC_A > SC_B) ? SC_A : SC_B;
  __shared__ __align__(16) f16 L[W2U + SCU];
  f16* Bs2 = L;
  f16* SC  = L + W2U;

  const int t = threadIdx.x;
  const int wid  = t >> 6;
  const int l    = t & 63;
  const int m15  = l & 15;
  const int quad = l >> 4;
  const int rw   = blockIdx.x * 128 + wid * 32;

  constexpr int W1W = K1PAD * 128 / 8;
  constexpr int W2W = NC2PAD * 128 / 8;
  for (int i = t; i < W1W; i += 256) ((f16x8*)SC)[i]  = ((const f16x8*)W1t)[i];
  for (int i = t; i < W2W; i += 256) ((f16x8*)Bs2)[i] = ((const f16x8*)W2t)[i];

  const f16* Xr0 = X + (size_t)(rw + m15) * RS1;
  const f16* Xr1 = X + (size_t)(rw + 16 + m15) * RS1;
  f16x8 a0r[KST1], a1r[KST1];
  #pragma unroll
  for (int ks = 0; ks < KST1; ++ks) {
    const int off = ks * 32 + quad * 8;
    a0r[ks] = *(const f16x8*)(Xr0 + off);
    a1r[ks] = *(const f16x8*)(Xr1 + off);
  }

  f16x8 xo[8];
  f16x2 xo2;
  if constexpr (MODE2 == 1) {
    const f16* xp = xor16 + (size_t)(blockIdx.x * 128 + (t >> 1)) * 160;
    #pragma unroll
    for (int c8 = 0; c8 < 8; ++c8)
      xo[c8] = *(const f16x8*)(xp + (t & 1) * 64 + c8 * 8);
    xo2 = *(const f16x2*)(xp + 128);
  }

  float b1r[NT1];
  #pragma unroll
  for (int nt = 0; nt < NT1; ++nt) b1r[nt] = b1[nt * 16 + m15];

  __syncthreads();

  f32x4 acc1[2][NT1];
  #pragma unroll
  for (int mt = 0; mt < 2; ++mt)
    #pragma unroll
    for (int nt = 0; nt < NT1; ++nt)
      acc1[mt][nt] = (f32x4){0.f, 0.f, 0.f, 0.f};

  #pragma unroll
  for (int ks = 0; ks < KST1; ++ks) {
    #pragma unroll
    for (int nt = 0; nt < NT1; ++nt) {
      f16x8 b = *((const f16x8*)SC + (nt * KST1 + ks) * 64 + l);
      acc1[0][nt] = __builtin_amdgcn_mfma_f32_16x16x32_f16(a0r[ks], b, acc1[0][nt], 0, 0, 0);
      acc1[1][nt] = __builtin_amdgcn_mfma_f32_16x16x32_f16(a1r[ks], b, acc1[1][nt], 0, 0, 0);
    }
  }

  __syncthreads();

  #pragma unroll
  for (int mt = 0; mt < 2; ++mt) {
    #pragma unroll
    for (int reg = 0; reg < 4; ++reg) {
      const int rl = wid * 32 + mt * 16 + quad * 4 + reg;
      #pragma unroll
      for (int nt = 0; nt < NT1; ++nt)
        SC[rl * PSTR1 + nt * 16 + m15] = (f16)sigm(acc1[mt][nt][reg] + b1r[nt]);
    }
  }
  __syncthreads();

  f32x4 acc2[2][NT2];
  #pragma unroll
  for (int mt = 0; mt < 2; ++mt)
    #pragma unroll
    for (int nt = 0; nt < NT2; ++nt)
      acc2[mt][nt] = (f32x4){0.f, 0.f, 0.f, 0.f};

  const int rA0 = wid * 32 + m15;
  const int rA1 = rA0 + 16;
  union A8 { f16x8 v; f16x4 q[2]; };
  #pragma unroll
  for (int ks = 0; ks < KST2; ++ks) {
    const int k0 = ks * 32 + quad * 8;
    A8 a0, a1;
    a0.q[0] = *(const f16x4*)&SC[rA0 * PSTR1 + k0];
    a0.q[1] = *(const f16x4*)&SC[rA0 * PSTR1 + k0 + 4];
    a1.q[0] = *(const f16x4*)&SC[rA1 * PSTR1 + k0];
    a1.q[1] = *(const f16x4*)&SC[rA1 * PSTR1 + k0 + 4];
    #pragma unroll
    for (int nt = 0; nt < NT2; ++nt) {
      f16x8 b = *((const f16x8*)Bs2 + (nt * KST2 + ks) * 64 + l);
      acc2[0][nt] = __builtin_amdgcn_mfma_f32_16x16x32_f16(a0.v, b, acc2[0][nt], 0, 0, 0);
      acc2[1][nt] = __builtin_amdgcn_mfma_f32_16x16x32_f16(a1.v, b, acc2[1][nt], 0, 0, 0);
    }
  }
  __syncthreads();

  #pragma unroll
  for (int mt = 0; mt < 2; ++mt) {
    #pragma unroll
    for (int reg = 0; reg < 4; ++reg) {
      const int rl = wid * 32 + mt * 16 + quad * 4 + reg;
      #pragma unroll
      for (int nt = 0; nt < NT2; ++nt)
        SC[rl * PSTR2 + nt * 16 + m15] = (f16)acc2[mt][nt][reg];
    }
  }
  __syncthreads();

  const int r  = t >> 1;
  const int hf = t & 1;
  const int gr = blockIdx.x * 128 + r;
  if (gr < n) {
    if constexpr (MODE2 == 0) {
      #pragma unroll
      for (int c8 = 0; c8 < 8; ++c8) {
        const int c0 = hf * 64 + c8 * 8;
        f16x8 v = *(const f16x8*)&SC[r * PSTR2 + c0];
        f16x8 o;
        #pragma unroll
        for (int j = 0; j < 8; ++j)
          o[j] = (f16)sigm((float)v[j] + b2[c0 + j]);
        *(f16x8*)&Y[(size_t)gr * YRS + c0] = o;
      }
    } else {
      const bool hasInit = (gr >= ngrid);
      #pragma unroll
      for (int c8 = 0; c8 < 8; ++c8) {
        const int c0 = hf * 64 + c8 * 8;
        f16x8 v = *(const f16x8*)&SC[r * PSTR2 + c0];
        f16x8 o;
        #pragma unroll
        for (int j = 0; j < 8; ++j) {
          const int col = c0 + j;
          float fv = sigm((float)v[j] + b2[col]);
          float xov = (float)xo[c8][j];
          float ip = hasInit ? initial[(size_t)(gr - ngrid) * 128 + col] : 0.0f;
          o[j] = (f16)(xov * fv + (1.0f - fv) * ip);
        }
        *(f16x8*)&Y[(size_t)gr * YRS + c0] = o;
      }
      if (hf) {
        #pragma unroll
        for (int k = 0; k < 2; ++k) {
          const int col = 128 + k;
          float fv = sigm((float)SC[r * PSTR2 + col] + b2[col]);
          Y[(size_t)gr * YRS + col] = (f16)((float)xo2[k] * fv);
        }
      }
    }
  }
}

// ---------------- fused aggregation + next-layer matmul ----------------
// Per block: 64 dests. Phase 1: each of 4 waves gathers+LNs 16 dests into an
// LDS H-tile (exactly the old agg body, H never touches HBM). Phase 2: the
// block runs the 64x128 @ 128x128 MFMA (B-frags straight from L2-hot Wt; no
// LDS W staging keeps LDS at 16.9 KB) and writes G = (H@W)*dinv.
// Kills 1 launch + 51 MB H round-trip per layer; the MFMA phase hides under
// other blocks' fabric-bound gather (MFMA pipe is otherwise idle in agg).
// LNMODE 0: relu(LN(...)); LNMODE 1: LN(...).
template<int LNMODE>
__global__ __launch_bounds__(256, 5) void aggmm_kernel(
    const f16* __restrict__ G, const int* __restrict__ ncnt,
    const int* __restrict__ dense, const float* __restrict__ dinv,
    const float* __restrict__ bias, const float* __restrict__ gamma,
    const float* __restrict__ beta, const f16* __restrict__ Wt,
    f16* __restrict__ Gout, int n)
{
  constexpr int PSTR = 132;  // %16==4: conflict-light transpose scatter
  __shared__ __align__(16) f16 Htile[64 * PSTR];

  const int t = threadIdx.x;
  const int wv = t >> 6, lane = t & 63;
  const int li = lane & 15, grp = lane >> 4;
  const int cbase = blockIdx.x * 64;

  union F8 { f16x8 h; int4 i; };

  // ---- phase 1: gather + LN, 16 dests per wave ----
  #pragma unroll 1
  for (int i = 0; i < 16; ++i) {
    const int lr = wv * 16 + i;
    const int c = cbase + lr;
    if (c < n) {
      const int nc = min(ncnt[c], DENSW);
      int raw = 0;
      if (lane < 32) raw = dense[(size_t)c * DENSW + lane];
      if (nc > 32) {
        if (lane >= 32) raw = dense[(size_t)c * DENSW + lane];
      }
      const int myidx = (lane < nc) ? raw : c;

      F8 m; m.h = *(const f16x8*)(G + (size_t)c * 128 + li * 8);  // self-loop
      F8 m2; m2.h = m.h;
      F8 m3; m3.h = m.h;
      F8 m4; m4.h = m.h;
      const int B = (nc + 3) >> 2;
      int b = 0;
      for (; b + 3 < B; b += 4) {
        int r0 = __shfl(myidx, (b + 0) * 4 + grp, 64);
        int r1 = __shfl(myidx, (b + 1) * 4 + grp, 64);
        int r2 = __shfl(myidx, (b + 2) * 4 + grp, 64);
        int r3 = __shfl(myidx, (b + 3) * 4 + grp, 64);
        F8 v0; v0.h = *(const f16x8*)(G + (size_t)r0 * 128 + li * 8);
        F8 v1; v1.h = *(const f16x8*)(G + (size_t)r1 * 128 + li * 8);
        F8 v2; v2.h = *(const f16x8*)(G + (size_t)r2 * 128 + li * 8);
        F8 v3; v3.h = *(const f16x8*)(G + (size_t)r3 * 128 + li * 8);
        m.h  = max8(m.h,  v0.h);
        m2.h = max8(m2.h, v1.h);
        m3.h = max8(m3.h, v2.h);
        m4.h = max8(m4.h, v3.h);
      }
      for (; b < B; ++b) {
        int r0 = __shfl(myidx, b * 4 + grp, 64);
        F8 v; v.h = *(const f16x8*)(G + (size_t)r0 * 128 + li * 8);
        m.h = max8(m.h, v.h);
      }
      m.h = max8(max8(m.h, m2.h), max8(m3.h, m4.h));

      #pragma unroll
      for (int st = 16; st <= 32; st <<= 1) {
        F8 o;
        #pragma unroll
        for (int d = 0; d < 4; ++d) o.i[d] = __shfl_xor(m.i[d], st, 64);
        m.h = max8(m.h, o.h);
      }

      const float dc = dinv[c];
      float v[8];
      float s = 0.f, sq = 0.f;
      #pragma unroll
      for (int j = 0; j < 8; ++j) {
        v[j] = (float)m.h[j] * dc + bias[li * 8 + j];
        s += v[j]; sq += v[j] * v[j];
      }
      #pragma unroll
      for (int st = 1; st <= 8; st <<= 1) {
        s  += __shfl_xor(s, st, 64);
        sq += __shfl_xor(sq, st, 64);
      }
      float mu  = s * (1.0f / 128.0f);
      float var = sq * (1.0f / 128.0f) - mu * mu;
      float rstd = rsqrtf(var + 1e-5f);
      if (grp == 0) {
        f16x8 ov;
        #pragma unroll
        for (int j = 0; j < 8; ++j) {
          float o = (v[j] - mu) * rstd * gamma[li * 8 + j] + beta[li * 8 + j];
          if constexpr (LNMODE == 0) o = fmaxf(o, 0.0f);
          ov[j] = (f16)o;
        }
        *(f16x8*)&Htile[lr * PSTR + li * 8] = ov;
      }
    }
  }
  __syncthreads();

  // ---- phase 2: 64x128 @ 128x128 MFMA; wave wv owns rows wv*16..+15 ----
  const int m15 = lane & 15, quad = lane >> 4;
  f16x8 a[4];
  #pragma unroll
  for (int ks = 0; ks < 4; ++ks)
    a[ks] = *(const f16x8*)&Htile[(wv * 16 + m15) * PSTR + ks * 32 + quad * 8];

  f32x4 acc[8];
  #pragma unroll
  for (int nt = 0; nt < 8; ++nt) acc[nt] = (f32x4){0.f, 0.f, 0.f, 0.f};
  #pragma unroll
  for (int ks = 0; ks < 4; ++ks) {
    #pragma unroll
    for (int nt = 0; nt < 8; ++nt) {
      f16x8 b = *((const f16x8*)Wt + (nt * 4 + ks) * 64 + lane);  // L2-hot
      acc[nt] = __builtin_amdgcn_mfma_f32_16x16x32_f16(a[ks], b, acc[nt], 0, 0, 0);
    }
  }
  __syncthreads();  // all waves done reading Htile

  // transpose scatter
  #pragma unroll
  for (int reg = 0; reg < 4; ++reg) {
    const int rl = wv * 16 + quad * 4 + reg;
    #pragma unroll
    for (int nt = 0; nt < 8; ++nt)
      Htile[rl * PSTR + nt * 16 + m15] = (f16)acc[nt][reg];
  }
  __syncthreads();

  // epilogue: G = row * dinv
  const int r  = t >> 2;
  const int cp = t & 3;
  const int gr = cbase + r;
  if (gr < n) {
    const float dv = dinv[gr];
    #pragma unroll
    for (int c8 = 0; c8 < 4; ++c8) {
      const int c0 = cp * 32 + c8 * 8;
      f16x8 v = *(const f16x8*)&Htile[r * PSTR + c0];
      f16x8 o;
      #pragma unroll
      for (int j = 0; j < 8; ++j) o[j] = (f16)((float)v[j] * dv);
      *(f16x8*)&Gout[(size_t)gr * 128 + c0] = o;
    }
  }
}

// ---------------- final aggregation (MODE 2 epilogue only) ----------------
__global__ __launch_bounds__(256) void aggfin_kernel(
    const f16* __restrict__ G, const int* __restrict__ ncnt,
    const int* __restrict__ dense, const float* __restrict__ dinv,
    const float* __restrict__ bias, const f16* __restrict__ xg,
    const f16* __restrict__ u, float* __restrict__ out, int n)
{
  const int wid = threadIdx.x >> 6, lane = threadIdx.x & 63;
  const int c = blockIdx.x * 4 + wid;
  if (c >= n) return;
  const int li = lane & 15, grp = lane >> 4;

  union F8 { f16x8 h; int4 i; };
  const int nc = min(ncnt[c], DENSW);
  int raw = 0;
  if (lane < 32) raw = dense[(size_t)c * DENSW + lane];
  if (nc > 32) {
    if (lane >= 32) raw = dense[(size_t)c * DENSW + lane];
  }
  const int myidx = (lane < nc) ? raw : c;

  F8 m; m.h = *(const f16x8*)(G + (size_t)c * 128 + li * 8);
  F8 m2; m2.h = m.h;
  F8 m3; m3.h = m.h;
  F8 m4; m4.h = m.h;
  const int B = (nc + 3) >> 2;
  int b = 0;
  for (; b + 3 < B; b += 4) {
    int r0 = __shfl(myidx, (b + 0) * 4 + grp, 64);
    int r1 = __shfl(myidx, (b + 1) * 4 + grp, 64);
    int r2 = __shfl(myidx, (b + 2) * 4 + grp, 64);
    int r3 = __shfl(myidx, (b + 3) * 4 + grp, 64);
    F8 v0; v0.h = *(const f16x8*)(G + (size_t)r0 * 128 + li * 8);
    F8 v1; v1.h = *(const f16x8*)(G + (size_t)r1 * 128 + li * 8);
    F8 v2; v2.h = *(const f16x8*)(G + (size_t)r2 * 128 + li * 8);
    F8 v3; v3.h = *(const f16x8*)(G + (size_t)r3 * 128 + li * 8);
    m.h  = max8(m.h,  v0.h);
    m2.h = max8(m2.h, v1.h);
    m3.h = max8(m3.h, v2.h);
    m4.h = max8(m4.h, v3.h);
  }
  for (; b < B; ++b) {
    int r0 = __shfl(myidx, b * 4 + grp, 64);
    F8 v; v.h = *(const f16x8*)(G + (size_t)r0 * 128 + li * 8);
    m.h = max8(m.h, v.h);
  }
  m.h = max8(max8(m.h, m2.h), max8(m3.h, m4.h));

  #pragma unroll
  for (int st = 16; st <= 32; st <<= 1) {
    F8 o;
    #pragma unroll
    for (int d = 0; d < 4; ++d) o.i[d] = __shfl_xor(m.i[d], st, 64);
    m.h = max8(m.h, o.h);
  }

  if (grp == 0) {
    const float dc = dinv[c];
    f16x8 xv = *(const f16x8*)(xg + (size_t)c * 160 + li * 8);
    f16x8 uv = *(const f16x8*)(u  + (size_t)c * 128 + li * 8);
    float o[8];
    #pragma unroll
    for (int j = 0; j < 8; ++j) {
      float v = (float)m.h[j] * dc + bias[li * 8 + j];
      o[j] = (float)xv[j] + v * (float)uv[j];
    }
    float* op = out + (size_t)c * 128 + li * 8;
    *(float4*)op       = make_float4(o[0], o[1], o[2], o[3]);
    *(float4*)(op + 4) = make_float4(o[4], o[5], o[6], o[7]);
  }
}

extern "C" void kernel_launch(void* const* d_in, const int* in_sizes, int n_in,
                              void* d_out, int out_size, void* d_ws, size_t ws_size,
                              hipStream_t stream) {
  (void)n_in; (void)out_size; (void)ws_size;
  const float* x       = (const float*)d_in[0];
  const int*   ei      = (const int*)d_in[1];
  const float* initial = (const float*)d_in[2];
  const float* Wf1 = (const float*)d_in[3];  const float* bf1 = (const float*)d_in[4];
  const float* Wf2 = (const float*)d_in[5];  const float* bf2 = (const float*)d_in[6];
  const float* Wu1 = (const float*)d_in[7];  const float* bu1 = (const float*)d_in[8];
  const float* Wu2 = (const float*)d_in[9];  const float* bu2 = (const float*)d_in[10];
  const float* Wc1 = (const float*)d_in[11]; const float* bc1 = (const float*)d_in[12];
  const float* Wc2 = (const float*)d_in[13]; const float* bc2 = (const float*)d_in[14];
  const float* Wc3 = (const float*)d_in[15]; const float* bc3 = (const float*)d_in[16];
  const float* Wc4 = (const float*)d_in[17]; const float* bc4 = (const float*)d_in[18];
  const float* Wco = (const float*)d_in[19]; const float* bco = (const float*)d_in[20];
  const float* g3  = (const float*)d_in[21]; const float* bn3 = (const float*)d_in[22];
  const float* g6  = (const float*)d_in[23]; const float* bn6 = (const float*)d_in[24];
  const float* g7  = (const float*)d_in[25]; const float* bn7 = (const float*)d_in[26];

  const int N  = in_sizes[0] / HC;   // 100000
  const int E  = in_sizes[1] / 2;    // 1600000
  const int NG = N - NIO;            // 99872
  const int NP = N + 128;            // padded rows for OOB-safe A-frag loads
  const int NB = (N + 127) / 128;    // 782 coarse buckets
  const int NSEG = 8 * SUBB;         // 64 append segments per bucket

  char* w = (char*)d_ws;
  auto carve = [&](size_t bytes) {
    char* p = w; w += (bytes + 255) & ~(size_t)255; return p;
  };
  int*      bcnt   = (int*)     carve((size_t)NB * NSEG * 4);
  unsigned* bucket = (unsigned*)carve((size_t)NB * NSEG * BCAP_S * 4);  // 25.6 MB
  int*      ncnt   = (int*)     carve((size_t)N * 4);
  int*      dense  = (int*)     carve((size_t)N * DENSW * 4);      // 25.6 MB
  float*    dinv   = (float*)   carve((size_t)N * 4);
  f16*      x16    = (f16*)     carve((size_t)NP * 160 * 2);
  f16*      xg     = (f16*)     carve((size_t)NP * 160 * 2);
  f16*      u      = (f16*)     carve((size_t)N  * 128 * 2);
  f16*      G      = (f16*)     carve((size_t)NP * 128 * 2);
  f16*      G2     = (f16*)     carve((size_t)NP * 128 * 2);
  f16*      Wt_f1  = (f16*)     carve(160 * 128 * 2);
  f16*      Wt_f2  = (f16*)     carve(128 * 144 * 2);
  f16*      Wt_u1  = (f16*)     carve(160 * 128 * 2);
  f16*      Wt_u2  = (f16*)     carve(128 * 128 * 2);
  f16*      Wt_c1  = (f16*)     carve(160 * 128 * 2);
  f16*      Wt_c2  = (f16*)     carve(128 * 128 * 2);
  f16*      Wt_c3  = (f16*)     carve(128 * 128 * 2);
  f16*      Wt_c4  = (f16*)     carve(128 * 128 * 2);
  f16*      Wt_co  = (f16*)     carve(128 * 128 * 2);

  const int* erow = ei;
  const int* ecol = ei + E;

  const int gE   = (E + 255) / 256;
  const int gM   = (N + 127) / 128;
  const int gM64 = (N + 63) / 64;
  const int gA   = (N + 3) / 4;
  const int gAM  = (N + 63) / 64;

  // fused prep: xprep (vectorized) + wprep + bcnt zero in ONE launch
  WAll wa;
  wa.m[0] = {Wf1, Wt_f1, HC,  HID, 160, 128};
  wa.m[1] = {Wf2, Wt_f2, HID, HC,  128, 144};
  wa.m[2] = {Wu1, Wt_u1, HC,  HID, 160, 128};
  wa.m[3] = {Wu2, Wt_u2, HID, HID, 128, 128};
  wa.m[4] = {Wc1, Wt_c1, HC,  HID, 160, 128};
  wa.m[5] = {Wc2, Wt_c2, HID, HID, 128, 128};
  wa.m[6] = {Wc3, Wt_c3, HID, HID, 128, 128};
  wa.m[7] = {Wc4, Wt_c4, HID, HID, 128, 128};
  wa.m[8] = {Wco, Wt_co, HID, HID, 128, 128};
  const int gX = (N * 20 + 255) / 256;
  const int gZ = (NB * NSEG + 255) / 256;
  prep_kernel<<<gX + 90 + gZ, 256, 0, stream>>>(x, x16, xg, N, wa, bcnt, NB * NSEG, gX);

  // graph build (two-level binning)
  binscatter_kernel<<<gE, 256, 0, stream>>>(erow, ecol, bcnt, bucket, E, NB);
  build_kernel<<<NB, 256, 0, stream>>>(bcnt, bucket, ncnt, dense, dinv, N, NB);

  // forget gate (f1+f2 fused): xg = mix(sigm(sigm(x@Wf1+bf1)@Wf2+bf2))
  mm_fused<160, 160, 144, 130, 1><<<gM, 256, 0, stream>>>(
      x16, Wt_f1, Wt_f2, bf1, bf2, xg, x16, initial, N, NG);
  // update gate (u1+u2 fused): u = sigm(sigm(xg@Wu1+bu1)@Wu2+bu2)
  mm_fused<160, 160, 128, 128, 0><<<gM, 256, 0, stream>>>(
      xg, Wt_u1, Wt_u2, bu1, bu2, u, nullptr, nullptr, N, NG);

  // gcn1 matmul (standalone): G = (xg @ Wc1) * dinv
  mm_mfma<160, 160, 128, 128, 2, 64><<<gM64, 256, 0, stream>>>(
      xg, Wt_c1, nullptr, G, dinv, nullptr, nullptr, N, NG);
  // agg1(relu LN) + gcn2 mm : G -> G2
  aggmm_kernel<0><<<gAM, 256, 0, stream>>>(G,  ncnt, dense, dinv, bc1, g3, bn3, Wt_c2, G2, N);
  // agg2(LN) + gcn3 mm : G2 -> G
  aggmm_kernel<1><<<gAM, 256, 0, stream>>>(G2, ncnt, dense, dinv, bc2, g3, bn3, Wt_c3, G,  N);
  // agg3(LN) + gcn4 mm : G -> G2
  aggmm_kernel<1><<<gAM, 256, 0, stream>>>(G,  ncnt, dense, dinv, bc3, g6, bn6, Wt_c4, G2, N);
  // agg4(LN) + gcn5 mm : G2 -> G
  aggmm_kernel<1><<<gAM, 256, 0, stream>>>(G2, ncnt, dense, dinv, bc4, g7, bn7, Wt_co, G,  N);
  // final: out = xg[:, :128] + (agg(G) + bco) * u
  aggfin_kernel<<<gA, 256, 0, stream>>>(G, ncnt, dense, dinv, bco, xg, u, (float*)d_out, N);
}

// Round 11
// 725.676 us; speedup vs baseline: 1.1059x; 1.1059x over previous
//
#include <hip/hip_runtime.h>
#include <cstdint>

#define HID 128
#define HC  130
#define NIO 128
#define DENSW 64     // dense ELL width (max in-degree ~45 for Poisson(16))
#define SUBB 8       // sub-cursors per (xcd,bucket): kills same-address atomic serialization
#define BCAP_S 128   // per-(xcd,sub,bucket) capacity; mean ~32 (+17 sigma), 25.6MB total

typedef _Float16 f16;
typedef _Float16 f16x2 __attribute__((ext_vector_type(2)));
typedef _Float16 f16x4 __attribute__((ext_vector_type(4)));
typedef _Float16 f16x8 __attribute__((ext_vector_type(8)));
typedef float    f32x4 __attribute__((ext_vector_type(4)));

__device__ __forceinline__ float sigm(float z) {
  return 1.0f / (1.0f + __expf(-z));
}

__device__ __forceinline__ int xcc_id() {
  int x;
  asm volatile("s_getreg_b32 %0, hwreg(HW_REG_XCC_ID)" : "=s"(x));
  return x & 7;
}

// Packed f16 max: v_pk_max_f16 does 2 elements/op (ternary lowers to
// v_cmp+v_cndmask = 4x the VALU). Inputs finite (sigmoid/LN outputs).
__device__ __forceinline__ f16x8 max8(f16x8 a, f16x8 b) {
  union P { f16x8 h; f16x2 p[4]; } A, B, O;
  A.h = a; B.h = b;
  #pragma unroll
  for (int i = 0; i < 4; ++i)
    asm("v_pk_max_f16 %0, %1, %2" : "=v"(O.p[i]) : "v"(A.p[i]), "v"(B.p[i]));
  return O.h;
}

// ---------------- prep mega-kernel ----------------
struct WDesc { const float* src; f16* dst; int K, NC, Kpad, NCpad; };
struct WAll { WDesc m[9]; };

__global__ __launch_bounds__(256) void prep_kernel(
    const float* __restrict__ x, f16* __restrict__ x16, f16* __restrict__ xg,
    int n, WAll wa, int* __restrict__ bcnt, int nzero, int gX) {
  const int bb = blockIdx.x;
  const int t = threadIdx.x;
  if (bb < gX) {
    int idx = bb * 256 + t;
    if (idx >= n * 20) return;
    int r = idx / 20, g = idx - r * 20;
    int c0 = g * 8;
    f16x8 o;
    #pragma unroll
    for (int j = 0; j < 8; ++j) {
      int c = c0 + j;
      o[j] = (f16)((c < HC) ? x[(size_t)r * HC + c] : 0.0f);
    }
    *(f16x8*)&x16[(size_t)r * 160 + c0] = o;
    if (c0 >= 136) {
      f16x8 z = (f16x8){0,0,0,0,0,0,0,0};
      *(f16x8*)&xg[(size_t)r * 160 + c0] = z;
    } else if (c0 == 128) {
      #pragma unroll
      for (int c = 130; c < 136; ++c) xg[(size_t)r * 160 + c] = (f16)0.0f;
    }
  } else if (bb < gX + 90) {
    const int wb = bb - gX;
    const WDesc d = wa.m[wb / 10];
    const int KST = d.Kpad >> 5;
    const int total = (d.NCpad >> 4) * KST * 64;
    int idx = (wb % 10) * 256 + t;
    if (idx >= total) return;
    int nt  = idx / (KST * 64);
    int rem = idx - nt * (KST * 64);
    int ks  = rem >> 6;
    int l   = rem & 63;
    int nn  = nt * 16 + (l & 15);
    int k0  = ks * 32 + (l >> 4) * 8;
    f16x8 o;
    #pragma unroll
    for (int j = 0; j < 8; ++j) {
      int k = k0 + j;
      float v = (k < d.K && nn < d.NC) ? d.src[(size_t)k * d.NC + nn] : 0.0f;
      o[j] = (f16)v;
    }
    *((f16x8*)d.dst + idx) = o;
  } else {
    int i = (bb - gX - 90) * 256 + t;
    if (i < nzero) bcnt[i] = 0;
  }
}

// ---------------- graph build: two-level binning ----------------
__global__ void binscatter_kernel(const int* __restrict__ row, const int* __restrict__ col,
    int* __restrict__ bcnt, unsigned* __restrict__ bucket, int e, int nb) {
  const int g0 = xcc_id() * SUBB + ((blockIdx.x >> 3) & (SUBB - 1));
  int i = blockIdx.x * blockDim.x + threadIdx.x;
  if (i >= e) return;
  int c = col[i], r = row[i];
  int b = c >> 7;
  int cur = atomicAdd(&bcnt[g0 * nb + b], 1);
  if (cur < BCAP_S)
    bucket[((size_t)g0 * nb + b) * BCAP_S + cur] = ((unsigned)r << 7) | (unsigned)(c & 127);
}

__global__ __launch_bounds__(256) void build_kernel(const int* __restrict__ bcnt,
    const unsigned* __restrict__ bucket, int* __restrict__ ncnt,
    int* __restrict__ dense, float* __restrict__ dinv, int n, int nb) {
  __shared__ int lcnt[128];
  const int b = blockIdx.x;
  const int t = threadIdx.x;
  if (t < 128) lcnt[t] = 0;
  __syncthreads();
  const int wv = t >> 6, ln = t & 63;
  #pragma unroll 1
  for (int g = wv * 16; g < wv * 16 + 16; ++g) {
    const int cntg = min(bcnt[g * nb + b], BCAP_S);
    const unsigned* __restrict__ src = bucket + ((size_t)g * nb + b) * BCAP_S;
    for (int idx = ln; idx < cntg; idx += 64) {
      unsigned ev = src[idx];
      int cl = (int)(ev & 127u);
      int r  = (int)(ev >> 7);
      int s = atomicAdd(&lcnt[cl], 1);
      if (s < DENSW) dense[(size_t)((b << 7) + cl) * DENSW + s] = r;
    }
  }
  __syncthreads();
  if (t < 128) {
    int c = (b << 7) + t;
    if (c < n) {
      int cc = min(lcnt[t], DENSW);
      ncnt[c] = cc;
      dinv[c] = rsqrtf((float)(cc + 1));  // +1 self-loop
    }
  }
}

// ---------------- MFMA matmul ----------------
// Y[N,NC] = X[N,K] @ W[K,NC]; MODE 0: sigm(acc+bias); MODE 2: acc*dinv[row].
// MROWS = rows per block (128 or 64). 64-row tiles double the grid (1563 vs
// 782 blocks, ~6/CU demand vs 3) so resident blocks sit at DIFFERENT phases
// and each other's memory phases get hidden (m114-style wave-level overlap).
template<int KPAD, int RS, int NCPAD, int NC, int MODE, int MROWS>
__global__ __launch_bounds__(256, 4) void mm_mfma(
    const f16* __restrict__ X, const f16* __restrict__ Wt,
    const float* __restrict__ bias, f16* __restrict__ Y,
    const float* __restrict__ dinv, const f16* __restrict__ xor16,
    const float* __restrict__ initial, int n, int ngrid)
{
  static_assert(MODE != 1 || MROWS == 128, "MODE1 only at 128 rows");
  constexpr int KST = KPAD / 32;
  constexpr int NT  = NCPAD / 16;
  constexpr int MT  = MROWS / 64;          // m-tiles per wave: 2 or 1
  constexpr int RPW = MROWS / 4;           // rows per wave: 32 or 16
  constexpr int YRS = (MODE == 1) ? 160 : 128;
  constexpr int PSTR = (NCPAD == 128) ? 132 : 148;  // %16 == 4
  constexpr int LDSH = (NCPAD * KPAD > MROWS * PSTR) ? NCPAD * KPAD : MROWS * PSTR;
  __shared__ __align__(16) f16 Bs[LDSH];

  const int t = threadIdx.x;
  const int wid  = t >> 6;
  const int l    = t & 63;
  const int m15  = l & 15;
  const int quad = l >> 4;
  const int rw   = blockIdx.x * MROWS + wid * RPW;

  constexpr int BSW = NCPAD * KPAD / 8;
  #pragma unroll
  for (int i = 0; i < (BSW + 255) / 256; ++i) {
    int idx = t + i * 256;
    if (BSW % 256 == 0 || idx < BSW)
      ((f16x8*)Bs)[idx] = ((const f16x8*)Wt)[idx];
  }

  const f16* Xr0 = X + (size_t)(rw + m15) * RS;
  const f16* Xr1 = X + (size_t)(rw + 16 + m15) * RS;  // used only if MT==2
  f16x8 a0r[KST], a1r[KST];
  #pragma unroll
  for (int ks = 0; ks < KST; ++ks) {
    const int off = ks * 32 + quad * 8;
    a0r[ks] = *(const f16x8*)(Xr0 + off);
    if constexpr (MT == 2) a1r[ks] = *(const f16x8*)(Xr1 + off);
  }

  // epilogue geometry: TPR threads per row, CSP cols per thread
  constexpr int TPR = 256 / MROWS;   // 2 or 4
  constexpr int CSP = 128 / TPR;     // 64 or 32
  const int r  = t / TPR;
  const int cp = t % TPR;
  const int gr = blockIdx.x * MROWS + r;
  float dv = 0.0f;
  if constexpr (MODE == 2) dv = (gr < n) ? dinv[gr] : 0.0f;

  f16x8 xo[CSP / 8];
  f16x2 xo2;
  if constexpr (MODE == 1) {
    const f16* xp = xor16 + (size_t)gr * 160;
    #pragma unroll
    for (int c8 = 0; c8 < CSP / 8; ++c8)
      xo[c8] = *(const f16x8*)(xp + cp * CSP + c8 * 8);
    xo2 = *(const f16x2*)(xp + 128);
  }

  __syncthreads();

  f32x4 acc[MT][NT];
  #pragma unroll
  for (int mt = 0; mt < MT; ++mt)
    #pragma unroll
    for (int nt = 0; nt < NT; ++nt)
      acc[mt][nt] = (f32x4){0.f, 0.f, 0.f, 0.f};

  #pragma unroll
  for (int ks = 0; ks < KST; ++ks) {
    #pragma unroll
    for (int nt = 0; nt < NT; ++nt) {
      f16x8 b = *((const f16x8*)Bs + (nt * KST + ks) * 64 + l);
      acc[0][nt] = __builtin_amdgcn_mfma_f32_16x16x32_f16(a0r[ks], b, acc[0][nt], 0, 0, 0);
      if constexpr (MT == 2)
        acc[1][nt] = __builtin_amdgcn_mfma_f32_16x16x32_f16(a1r[ks], b, acc[1][nt], 0, 0, 0);
    }
  }

  __syncthreads();  // done reading Bs; reuse as transpose tile

  #pragma unroll
  for (int mt = 0; mt < MT; ++mt) {
    #pragma unroll
    for (int reg = 0; reg < 4; ++reg) {
      const int rl = wid * RPW + mt * 16 + quad * 4 + reg;
      #pragma unroll
      for (int nt = 0; nt < NT; ++nt)
        Bs[rl * PSTR + nt * 16 + m15] = (f16)acc[mt][nt][reg];
    }
  }
  __syncthreads();

  if (gr < n) {
    if constexpr (MODE == 0 || MODE == 2) {
      #pragma unroll
      for (int c8 = 0; c8 < CSP / 8; ++c8) {
        const int c0 = cp * CSP + c8 * 8;
        f16x8 v = *(const f16x8*)&Bs[r * PSTR + c0];
        f16x8 o;
        #pragma unroll
        for (int j = 0; j < 8; ++j) {
          float a = (float)v[j];
          if constexpr (MODE == 0) o[j] = (f16)sigm(a + bias[c0 + j]);
          else                     o[j] = (f16)(a * dv);
        }
        *(f16x8*)&Y[(size_t)gr * YRS + c0] = o;
      }
    } else {  // MODE 1, NC=130 (MROWS==128, TPR==2)
      const bool hasInit = (gr >= ngrid);
      #pragma unroll
      for (int c8 = 0; c8 < CSP / 8; ++c8) {
        const int c0 = cp * CSP + c8 * 8;
        f16x8 v = *(const f16x8*)&Bs[r * PSTR + c0];
        f16x8 o;
        #pragma unroll
        for (int j = 0; j < 8; ++j) {
          const int col = c0 + j;
          float fv = sigm((float)v[j] + bias[col]);
          float xov = (float)xo[c8][j];
          float ip = hasInit ? initial[(size_t)(gr - ngrid) * 128 + col] : 0.0f;
          o[j] = (f16)(xov * fv + (1.0f - fv) * ip);
        }
        *(f16x8*)&Y[(size_t)gr * YRS + c0] = o;
      }
      if (cp == 1) {
        #pragma unroll
        for (int k = 0; k < 2; ++k) {
          const int col = 128 + k;
          float fv = sigm((float)Bs[r * PSTR + col] + bias[col]);
          Y[(size_t)gr * YRS + col] = (f16)((float)xo2[k] * fv);
        }
      }
    }
  }
}

// ---------------- fused two-layer MLP ----------------
// Y = epilogue2( sigm(X@W1 + b1) @ W2 + b2 ); S lives only in LDS.
template<int K1PAD, int RS1, int NC2PAD, int NC2, int MODE2>
__global__ __launch_bounds__(256, 2) void mm_fused(
    const f16* __restrict__ X, const f16* __restrict__ W1t, const f16* __restrict__ W2t,
    const float* __restrict__ b1, const float* __restrict__ b2, f16* __restrict__ Y,
    const f16* __restrict__ xor16, const float* __restrict__ initial, int n, int ngrid)
{
  constexpr int KST1 = K1PAD / 32;   // 5
  constexpr int NT1  = 8;            // mid = 128 cols
  constexpr int KST2 = 4;            // K2 = 128
  constexpr int NT2  = NC2PAD / 16;  // 8 or 9
  constexpr int PSTR1 = 132;         // %16==4: conflict-light scatter
  constexpr int PSTR2 = (NC2PAD == 128) ? 132 : 148;
  constexpr int YRS  = (MODE2 == 1) ? 160 : 128;
  constexpr int W2U  = NC2PAD * 128;                 // f16 units
  constexpr int SC_A = K1PAD * 128;                  // W1 frag area
  constexpr int SC_B = 128 * PSTR2;                  // tr2 area (>= tr1)
  constexpr int SCU  = (SC_A > SC_B) ? SC_A : SC_B;
  __shared__ __align__(16) f16 L[W2U + SCU];
  f16* Bs2 = L;
  f16* SC  = L + W2U;

  const int t = threadIdx.x;
  const int wid  = t >> 6;
  const int l    = t & 63;
  const int m15  = l & 15;
  const int quad = l >> 4;
  const int rw   = blockIdx.x * 128 + wid * 32;

  constexpr int W1W = K1PAD * 128 / 8;
  constexpr int W2W = NC2PAD * 128 / 8;
  for (int i = t; i < W1W; i += 256) ((f16x8*)SC)[i]  = ((const f16x8*)W1t)[i];
  for (int i = t; i < W2W; i += 256) ((f16x8*)Bs2)[i] = ((const f16x8*)W2t)[i];

  const f16* Xr0 = X + (size_t)(rw + m15) * RS1;
  const f16* Xr1 = X + (size_t)(rw + 16 + m15) * RS1;
  f16x8 a0r[KST1], a1r[KST1];
  #pragma unroll
  for (int ks = 0; ks < KST1; ++ks) {
    const int off = ks * 32 + quad * 8;
    a0r[ks] = *(const f16x8*)(Xr0 + off);
    a1r[ks] = *(const f16x8*)(Xr1 + off);
  }

  f16x8 xo[8];
  f16x2 xo2;
  if constexpr (MODE2 == 1) {
    const f16* xp = xor16 + (size_t)(blockIdx.x * 128 + (t >> 1)) * 160;
    #pragma unroll
    for (int c8 = 0; c8 < 8; ++c8)
      xo[c8] = *(const f16x8*)(xp + (t & 1) * 64 + c8 * 8);
    xo2 = *(const f16x2*)(xp + 128);
  }

  float b1r[NT1];
  #pragma unroll
  for (int nt = 0; nt < NT1; ++nt) b1r[nt] = b1[nt * 16 + m15];

  __syncthreads();

  // ---- stage 1: acc1 = X @ W1 ----
  f32x4 acc1[2][NT1];
  #pragma unroll
  for (int mt = 0; mt < 2; ++mt)
    #pragma unroll
    for (int nt = 0; nt < NT1; ++nt)
      acc1[mt][nt] = (f32x4){0.f, 0.f, 0.f, 0.f};

  #pragma unroll
  for (int ks = 0; ks < KST1; ++ks) {
    #pragma unroll
    for (int nt = 0; nt < NT1; ++nt) {
      f16x8 b = *((const f16x8*)SC + (nt * KST1 + ks) * 64 + l);
      acc1[0][nt] = __builtin_amdgcn_mfma_f32_16x16x32_f16(a0r[ks], b, acc1[0][nt], 0, 0, 0);
      acc1[1][nt] = __builtin_amdgcn_mfma_f32_16x16x32_f16(a1r[ks], b, acc1[1][nt], 0, 0, 0);
    }
  }

  __syncthreads();  // all waves done reading W1 -> SC reusable

  // ---- scatter S = sigm(acc1 + b1) into SC (row-major, stride PSTR1) ----
  #pragma unroll
  for (int mt = 0; mt < 2; ++mt) {
    #pragma unroll
    for (int reg = 0; reg < 4; ++reg) {
      const int rl = wid * 32 + mt * 16 + quad * 4 + reg;
      #pragma unroll
      for (int nt = 0; nt < NT1; ++nt)
        SC[rl * PSTR1 + nt * 16 + m15] = (f16)sigm(acc1[mt][nt][reg] + b1r[nt]);
    }
  }
  __syncthreads();

  // ---- stage 2: acc2 = S @ W2 ----
  f32x4 acc2[2][NT2];
  #pragma unroll
  for (int mt = 0; mt < 2; ++mt)
    #pragma unroll
    for (int nt = 0; nt < NT2; ++nt)
      acc2[mt][nt] = (f32x4){0.f, 0.f, 0.f, 0.f};

  const int rA0 = wid * 32 + m15;
  const int rA1 = rA0 + 16;
  union A8 { f16x8 v; f16x4 q[2]; };
  #pragma unroll
  for (int ks = 0; ks < KST2; ++ks) {
    const int k0 = ks * 32 + quad * 8;
    A8 a0, a1;
    a0.q[0] = *(const f16x4*)&SC[rA0 * PSTR1 + k0];
    a0.q[1] = *(const f16x4*)&SC[rA0 * PSTR1 + k0 + 4];
    a1.q[0] = *(const f16x4*)&SC[rA1 * PSTR1 + k0];
    a1.q[1] = *(const f16x4*)&SC[rA1 * PSTR1 + k0 + 4];
    #pragma unroll
    for (int nt = 0; nt < NT2; ++nt) {
      f16x8 b = *((const f16x8*)Bs2 + (nt * KST2 + ks) * 64 + l);
      acc2[0][nt] = __builtin_amdgcn_mfma_f32_16x16x32_f16(a0.v, b, acc2[0][nt], 0, 0, 0);
      acc2[1][nt] = __builtin_amdgcn_mfma_f32_16x16x32_f16(a1.v, b, acc2[1][nt], 0, 0, 0);
    }
  }
  __syncthreads();  // done reading S -> SC reusable for tr2

  #pragma unroll
  for (int mt = 0; mt < 2; ++mt) {
    #pragma unroll
    for (int reg = 0; reg < 4; ++reg) {
      const int rl = wid * 32 + mt * 16 + quad * 4 + reg;
      #pragma unroll
      for (int nt = 0; nt < NT2; ++nt)
        SC[rl * PSTR2 + nt * 16 + m15] = (f16)acc2[mt][nt][reg];
    }
  }
  __syncthreads();

  const int r  = t >> 1;
  const int hf = t & 1;
  const int gr = blockIdx.x * 128 + r;
  if (gr < n) {
    if constexpr (MODE2 == 0) {
      #pragma unroll
      for (int c8 = 0; c8 < 8; ++c8) {
        const int c0 = hf * 64 + c8 * 8;
        f16x8 v = *(const f16x8*)&SC[r * PSTR2 + c0];
        f16x8 o;
        #pragma unroll
        for (int j = 0; j < 8; ++j)
          o[j] = (f16)sigm((float)v[j] + b2[c0 + j]);
        *(f16x8*)&Y[(size_t)gr * YRS + c0] = o;
      }
    } else {  // MODE2 == 1, NC2 = 130
      const bool hasInit = (gr >= ngrid);
      #pragma unroll
      for (int c8 = 0; c8 < 8; ++c8) {
        const int c0 = hf * 64 + c8 * 8;
        f16x8 v = *(const f16x8*)&SC[r * PSTR2 + c0];
        f16x8 o;
        #pragma unroll
        for (int j = 0; j < 8; ++j) {
          const int col = c0 + j;
          float fv = sigm((float)v[j] + b2[col]);
          float xov = (float)xo[c8][j];
          float ip = hasInit ? initial[(size_t)(gr - ngrid) * 128 + col] : 0.0f;
          o[j] = (f16)(xov * fv + (1.0f - fv) * ip);
        }
        *(f16x8*)&Y[(size_t)gr * YRS + c0] = o;
      }
      if (hf) {
        #pragma unroll
        for (int k = 0; k < 2; ++k) {
          const int col = 128 + k;
          float fv = sigm((float)SC[r * PSTR2 + col] + b2[col]);
          Y[(size_t)gr * YRS + col] = (f16)((float)xo2[k] * fv);
        }
      }
    }
  }
}

// ---------------- aggregation (lane-group batched gather) ----------------
template<int MODE>
__global__ __launch_bounds__(256) void agg_kernel(
    const f16* __restrict__ G, const int* __restrict__ ncnt,
    const int* __restrict__ dense,
    const float* __restrict__ dinv, const float* __restrict__ bias,
    const float* __restrict__ gamma, const float* __restrict__ beta,
    const f16* __restrict__ xg, const f16* __restrict__ u,
    void* __restrict__ out, int n)
{
  const int wid = threadIdx.x >> 6, lane = threadIdx.x & 63;
  const int c = blockIdx.x * 4 + wid;
  if (c >= n) return;
  const int li = lane & 15, grp = lane >> 4;

  union F8 { f16x8 h; int4 i; };
  const int nc = min(ncnt[c], DENSW);
  int raw = 0;
  if (lane < 32) raw = dense[(size_t)c * DENSW + lane];  // coalesced 128B
  if (nc > 32) {                                         // rare, wave-uniform
    if (lane >= 32) raw = dense[(size_t)c * DENSW + lane];
  }
  const int myidx = (lane < nc) ? raw : c;               // self row is max-idempotent

  F8 m; m.h = *(const f16x8*)(G + (size_t)c * 128 + li * 8);  // self-loop
  F8 m2; m2.h = m.h;
  F8 m3; m3.h = m.h;
  F8 m4; m4.h = m.h;
  const int B = (nc + 3) >> 2;
  int b = 0;
  for (; b + 3 < B; b += 4) {
    int r0 = __shfl(myidx, (b + 0) * 4 + grp, 64);
    int r1 = __shfl(myidx, (b + 1) * 4 + grp, 64);
    int r2 = __shfl(myidx, (b + 2) * 4 + grp, 64);
    int r3 = __shfl(myidx, (b + 3) * 4 + grp, 64);
    F8 v0; v0.h = *(const f16x8*)(G + (size_t)r0 * 128 + li * 8);
    F8 v1; v1.h = *(const f16x8*)(G + (size_t)r1 * 128 + li * 8);
    F8 v2; v2.h = *(const f16x8*)(G + (size_t)r2 * 128 + li * 8);
    F8 v3; v3.h = *(const f16x8*)(G + (size_t)r3 * 128 + li * 8);
    m.h  = max8(m.h,  v0.h);
    m2.h = max8(m2.h, v1.h);
    m3.h = max8(m3.h, v2.h);
    m4.h = max8(m4.h, v3.h);
  }
  for (; b < B; ++b) {
    int r0 = __shfl(myidx, b * 4 + grp, 64);
    F8 v; v.h = *(const f16x8*)(G + (size_t)r0 * 128 + li * 8);
    m.h = max8(m.h, v.h);
  }
  m.h = max8(max8(m.h, m2.h), max8(m3.h, m4.h));

  #pragma unroll
  for (int st = 16; st <= 32; st <<= 1) {
    F8 o;
    #pragma unroll
    for (int d = 0; d < 4; ++d) o.i[d] = __shfl_xor(m.i[d], st, 64);
    m.h = max8(m.h, o.h);
  }

  const float dc = dinv[c];
  float v[8];
  float s = 0.f, sq = 0.f;
  #pragma unroll
  for (int j = 0; j < 8; ++j) {
    v[j] = (float)m.h[j] * dc + bias[li * 8 + j];
    s += v[j]; sq += v[j] * v[j];
  }

  if constexpr (MODE == 2) {
    if (grp == 0) {
      f16x8 xv = *(const f16x8*)(xg + (size_t)c * 160 + li * 8);
      f16x8 uv = *(const f16x8*)(u  + (size_t)c * 128 + li * 8);
      float o[8];
      #pragma unroll
      for (int j = 0; j < 8; ++j) o[j] = (float)xv[j] + v[j] * (float)uv[j];
      float* op = (float*)out + (size_t)c * 128 + li * 8;
      *(float4*)op       = make_float4(o[0], o[1], o[2], o[3]);
      *(float4*)(op + 4) = make_float4(o[4], o[5], o[6], o[7]);
    }
  } else {
    #pragma unroll
    for (int st = 1; st <= 8; st <<= 1) {
      s  += __shfl_xor(s, st, 64);
      sq += __shfl_xor(sq, st, 64);
    }
    float mu  = s * (1.0f / 128.0f);
    float var = sq * (1.0f / 128.0f) - mu * mu;
    float rstd = rsqrtf(var + 1e-5f);
    if (grp == 0) {
      f16x8 ov;
      #pragma unroll
      for (int j = 0; j < 8; ++j) {
        float o = (v[j] - mu) * rstd * gamma[li * 8 + j] + beta[li * 8 + j];
        if constexpr (MODE == 0) o = fmaxf(o, 0.0f);
        ov[j] = (f16)o;
      }
      *(f16x8*)((f16*)out + (size_t)c * 128 + li * 8) = ov;
    }
  }
}

extern "C" void kernel_launch(void* const* d_in, const int* in_sizes, int n_in,
                              void* d_out, int out_size, void* d_ws, size_t ws_size,
                              hipStream_t stream) {
  (void)n_in; (void)out_size; (void)ws_size;
  const float* x       = (const float*)d_in[0];
  const int*   ei      = (const int*)d_in[1];
  const float* initial = (const float*)d_in[2];
  const float* Wf1 = (const float*)d_in[3];  const float* bf1 = (const float*)d_in[4];
  const float* Wf2 = (const float*)d_in[5];  const float* bf2 = (const float*)d_in[6];
  const float* Wu1 = (const float*)d_in[7];  const float* bu1 = (const float*)d_in[8];
  const float* Wu2 = (const float*)d_in[9];  const float* bu2 = (const float*)d_in[10];
  const float* Wc1 = (const float*)d_in[11]; const float* bc1 = (const float*)d_in[12];
  const float* Wc2 = (const float*)d_in[13]; const float* bc2 = (const float*)d_in[14];
  const float* Wc3 = (const float*)d_in[15]; const float* bc3 = (const float*)d_in[16];
  const float* Wc4 = (const float*)d_in[17]; const float* bc4 = (const float*)d_in[18];
  const float* Wco = (const float*)d_in[19]; const float* bco = (const float*)d_in[20];
  const float* g3  = (const float*)d_in[21]; const float* bn3 = (const float*)d_in[22];
  const float* g6  = (const float*)d_in[23]; const float* bn6 = (const float*)d_in[24];
  const float* g7  = (const float*)d_in[25]; const float* bn7 = (const float*)d_in[26];

  const int N  = in_sizes[0] / HC;   // 100000
  const int E  = in_sizes[1] / 2;    // 1600000
  const int NG = N - NIO;            // 99872
  const int NP = N + 128;            // padded rows for OOB-safe A-frag loads
  const int NB = (N + 127) / 128;    // 782 coarse buckets
  const int NSEG = 8 * SUBB;         // 64 append segments per bucket

  char* w = (char*)d_ws;
  auto carve = [&](size_t bytes) {
    char* p = w; w += (bytes + 255) & ~(size_t)255; return p;
  };
  int*      bcnt   = (int*)     carve((size_t)NB * NSEG * 4);
  unsigned* bucket = (unsigned*)carve((size_t)NB * NSEG * BCAP_S * 4);  // 25.6 MB
  int*      ncnt   = (int*)     carve((size_t)N * 4);
  int*      dense  = (int*)     carve((size_t)N * DENSW * 4);      // 25.6 MB
  float*    dinv   = (float*)   carve((size_t)N * 4);
  f16*      x16    = (f16*)     carve((size_t)NP * 160 * 2);
  f16*      xg     = (f16*)     carve((size_t)NP * 160 * 2);
  f16*      u      = (f16*)     carve((size_t)N  * 128 * 2);
  f16*      G      = (f16*)     carve((size_t)N  * 128 * 2);
  f16*      H      = (f16*)     carve((size_t)NP * 128 * 2);
  f16*      Wt_f1  = (f16*)     carve(160 * 128 * 2);
  f16*      Wt_f2  = (f16*)     carve(128 * 144 * 2);
  f16*      Wt_u1  = (f16*)     carve(160 * 128 * 2);
  f16*      Wt_u2  = (f16*)     carve(128 * 128 * 2);
  f16*      Wt_c1  = (f16*)     carve(160 * 128 * 2);
  f16*      Wt_c2  = (f16*)     carve(128 * 128 * 2);
  f16*      Wt_c3  = (f16*)     carve(128 * 128 * 2);
  f16*      Wt_c4  = (f16*)     carve(128 * 128 * 2);
  f16*      Wt_co  = (f16*)     carve(128 * 128 * 2);

  const int* erow = ei;
  const int* ecol = ei + E;

  const int gE  = (E + 255) / 256;
  const int gM  = (N + 127) / 128;
  const int gM64 = (N + 63) / 64;
  const int gA  = (N + 3) / 4;

  // fused prep: xprep (vectorized) + wprep + bcnt zero in ONE launch
  WAll wa;
  wa.m[0] = {Wf1, Wt_f1, HC,  HID, 160, 128};
  wa.m[1] = {Wf2, Wt_f2, HID, HC,  128, 144};
  wa.m[2] = {Wu1, Wt_u1, HC,  HID, 160, 128};
  wa.m[3] = {Wu2, Wt_u2, HID, HID, 128, 128};
  wa.m[4] = {Wc1, Wt_c1, HC,  HID, 160, 128};
  wa.m[5] = {Wc2, Wt_c2, HID, HID, 128, 128};
  wa.m[6] = {Wc3, Wt_c3, HID, HID, 128, 128};
  wa.m[7] = {Wc4, Wt_c4, HID, HID, 128, 128};
  wa.m[8] = {Wco, Wt_co, HID, HID, 128, 128};
  const int gX = (N * 20 + 255) / 256;
  const int gZ = (NB * NSEG + 255) / 256;
  prep_kernel<<<gX + 90 + gZ, 256, 0, stream>>>(x, x16, xg, N, wa, bcnt, NB * NSEG, gX);

  // graph build (two-level binning)
  binscatter_kernel<<<gE, 256, 0, stream>>>(erow, ecol, bcnt, bucket, E, NB);
  build_kernel<<<NB, 256, 0, stream>>>(bcnt, bucket, ncnt, dense, dinv, N, NB);

  // forget gate (f1+f2 fused): xg = mix(sigm(sigm(x@Wf1+bf1)@Wf2+bf2))
  mm_fused<160, 160, 144, 130, 1><<<gM, 256, 0, stream>>>(
      x16, Wt_f1, Wt_f2, bf1, bf2, xg, x16, initial, N, NG);
  // update gate (u1+u2 fused): u = sigm(sigm(xg@Wu1+bu1)@Wu2+bu2)
  mm_fused<160, 160, 128, 128, 0><<<gM, 256, 0, stream>>>(
      xg, Wt_u1, Wt_u2, bu1, bu2, u, nullptr, nullptr, N, NG);

  // gcn1: relu(LN(..., g3, bn3))   -- 64-row tiles for TLP
  mm_mfma<160, 160, 128, 128, 2, 64><<<gM64, 256, 0, stream>>>(xg, Wt_c1, nullptr, G, dinv, nullptr, nullptr, N, NG);
  agg_kernel<0><<<gA, 256, 0, stream>>>(G, ncnt, dense, dinv, bc1, g3, bn3, nullptr, nullptr, H, N);
  // gcn2: LN(..., g3, bn3)
  mm_mfma<128, 128, 128, 128, 2, 64><<<gM64, 256, 0, stream>>>(H, Wt_c2, nullptr, G, dinv, nullptr, nullptr, N, NG);
  agg_kernel<1><<<gA, 256, 0, stream>>>(G, ncnt, dense, dinv, bc2, g3, bn3, nullptr, nullptr, H, N);
  // gcn3: LN(..., g6, bn6)
  mm_mfma<128, 128, 128, 128, 2, 64><<<gM64, 256, 0, stream>>>(H, Wt_c3, nullptr, G, dinv, nullptr, nullptr, N, NG);
  agg_kernel<1><<<gA, 256, 0, stream>>>(G, ncnt, dense, dinv, bc3, g6, bn6, nullptr, nullptr, H, N);
  // gcn4: LN(..., g7, bn7)
  mm_mfma<128, 128, 128, 128, 2, 64><<<gM64, 256, 0, stream>>>(H, Wt_c4, nullptr, G, dinv, nullptr, nullptr, N, NG);
  agg_kernel<1><<<gA, 256, 0, stream>>>(G, ncnt, dense, dinv, bc4, g7, bn7, nullptr, nullptr, H, N);
  // gcn5 + final: out = xg[:, :128] + (agg + bco) * u
  mm_mfma<128, 128, 128, 128, 2, 64><<<gM64, 256, 0, stream>>>(H, Wt_co, nullptr, G, dinv, nullptr, nullptr, N, NG);
  agg_kernel<2><<<gA, 256, 0, stream>>>(G, ncnt, dense, dinv, bco, nullptr, nullptr, xg, u, d_out, N);
}